// Round 4
// baseline (211.708 us; speedup 1.0000x reference)
//
#include <hip/hip_runtime.h>
#include <hip/hip_bf16.h>
#include <stdint.h>

#define IC 32
#define OC 32
#define HID 32

// Angle binning: per node, PBIN u64 cells of (count << TSH | sum of t*2^20),
// stored IN-PLACE in the output buffer (one node row = 32 floats = 16 u64).
// count field: 20 bits (max 1M >= A=400k). t-sum: 44 bits (A*2^20 < 2^39).
#define PBIN 16
#define TSH 44
#define TSCALE 1048576.0f   // 2^20

typedef __attribute__((ext_vector_type(8))) _Float16 half8;
typedef __attribute__((ext_vector_type(4))) float f32x4;
typedef unsigned long long u64;

static __device__ __forceinline__ _Float16 f2h(float f) { return (_Float16)f; }

// ---------------------------------------------------------------------------
// Zero-init output (also clears the in-place binning cells)
// ---------------------------------------------------------------------------
__global__ void zero_kernel(float* __restrict__ out, int n) {
    int i = (blockIdx.x * blockDim.x + threadIdx.x) * 4;
    if (i + 3 < n) {
        *(float4*)(out + i) = make_float4(0.f, 0.f, 0.f, 0.f);
    } else {
        for (int k = i; k < n; ++k) out[k] = 0.f;
    }
}

// ---------------------------------------------------------------------------
// Angle stage 1: classify each angle onto its linear piece of
//   feat(t) = relu(t*aW1 + ab1) @ aW2 + ab2   (piecewise-linear in scalar t)
// Piece id c(t) = # hinges in their t->+inf state (monotone in t; equal c
// => identical relu mask => feat linear over the group). Accumulate
// (count, sum-of-t) per (node, piece) with ONE u64 atomic per angle,
// directly into out[] reinterpreted as u64 cells (cleared by zero_kernel).
// ---------------------------------------------------------------------------
__global__ __launch_bounds__(256) void angle_scatter(
    const float* __restrict__ angles, const int* __restrict__ angle_index,
    const float* __restrict__ aW1, const float* __restrict__ ab1,
    u64* __restrict__ cells, int A)
{
    float w1[HID], b1[HID];
#pragma unroll
    for (int k = 0; k < HID; ++k) { w1[k] = aW1[k]; b1[k] = ab1[k]; }

    int i0 = blockIdx.x * blockDim.x + threadIdx.x;
    int stride = gridDim.x * blockDim.x;
    for (int a = i0; a < A; a += stride) {
        const float t = angles[a];
        const int j = angle_index[A + a];   // center node
        int c = 0, c0 = 0;
#pragma unroll
        for (int k = 0; k < HID; ++k) {
            const bool pos = w1[k] > 0.f;
            const bool on  = fmaf(t, w1[k], b1[k]) > 0.f;
            const bool on0 = b1[k] > 0.f;
            c  += (pos ? on  : !on ) ? 1 : 0;
            c0 += (pos ? on0 : !on0) ? 1 : 0;
        }
        const int cc = c - c0;
        if ((unsigned)cc < (unsigned)PBIN) {
            const u64 enc = ((u64)1 << TSH) | (u64)(unsigned)(t * TSCALE);
            atomicAdd(cells + (size_t)j * PBIN + cc, enc);
        }
        // cc >= PBIN (requires >16 realized pieces) handled by angle_fixup
    }
}

// ---------------------------------------------------------------------------
// Angle stage 2: per node, decode its 16 cells and evaluate
//   sum_pieces cnt * feat(tsum/cnt)    (exact: feat linear on each piece,
//   and the group mean stays inside the piece interval).
// 2 nodes per wave (32 lanes = 32 output channels). Reads the node's own
// row as u64, then OVERWRITES it with the fp32 result.
// ---------------------------------------------------------------------------
__global__ __launch_bounds__(256) void angle_gather(
    float* __restrict__ out,
    const float* __restrict__ aW1, const float* __restrict__ ab1,
    const float* __restrict__ aW2, const float* __restrict__ ab2,
    int N)
{
    const int lane = threadIdx.x & 63;
    const int o    = lane & 31;
    const int half = lane >> 5;
    const int wib  = threadIdx.x >> 6;
    const int gw   = blockIdx.x * (blockDim.x >> 6) + wib;
    const int nodesPerIter = gridDim.x * (blockDim.x >> 6) * 2;

    float w1[HID], b1[HID], w2[HID];
#pragma unroll
    for (int k = 0; k < HID; ++k) {
        w1[k] = aW1[k];
        b1[k] = ab1[k];
        w2[k] = aW2[k * OC + o];
    }
    const float bias = ab2[o];

    for (int j = gw * 2 + half; j < N; j += nodesPerIter) {
        const u64* cj = (const u64*)out + (size_t)j * PBIN;
        float acc = 0.f, tot = 0.f;
#pragma unroll
        for (int cc = 0; cc < PBIN; ++cc) {
            const u64 v = cj[cc];
            if (v) {
                const float n  = (float)(unsigned)(v >> TSH);
                const float ts = (float)(v & (((u64)1 << TSH) - 1)) * (1.f / TSCALE);
                const float tb = ts / n;
                float s = 0.f;
#pragma unroll
                for (int k = 0; k < HID; ++k) {
                    float h = fmaf(tb, w1[k], b1[k]);
                    h = h > 0.f ? h : 0.f;
                    s = fmaf(h, w2[k], s);
                }
                acc = fmaf(n, s, acc);
                tot += n;
            }
        }
        out[(size_t)j * OC + o] = fmaf(tot, bias, acc);
    }
}

// ---------------------------------------------------------------------------
// Fixup for angles whose piece index exceeds PBIN (only possible if the
// weight draw realizes >16 pieces on t in [0,1); expected ZERO work --
// uniform early-exit). Runs AFTER gather, adds exact feat via atomics.
// ---------------------------------------------------------------------------
__global__ __launch_bounds__(256) void angle_fixup(
    const float* __restrict__ angles, const int* __restrict__ angle_index,
    const float* __restrict__ aW1, const float* __restrict__ ab1,
    const float* __restrict__ aW2, const float* __restrict__ ab2,
    float* __restrict__ out, int A)
{
    float w1[HID], b1[HID];
#pragma unroll
    for (int k = 0; k < HID; ++k) { w1[k] = aW1[k]; b1[k] = ab1[k]; }

    int c0 = 0, c1 = 0;
#pragma unroll
    for (int k = 0; k < HID; ++k) {
        const bool pos = w1[k] > 0.f;
        const bool f0 = pos ? (b1[k] > 0.f) : !(b1[k] > 0.f);
        const bool f1 = pos ? ((w1[k] + b1[k]) > 0.f) : !((w1[k] + b1[k]) > 0.f);
        c0 += f0 ? 1 : 0;
        c1 += f1 ? 1 : 0;
    }
    if (c1 - c0 + 1 <= PBIN) return;   // uniform: no overflow possible

    int i0 = blockIdx.x * blockDim.x + threadIdx.x;
    int stride = gridDim.x * blockDim.x;
    for (int a = i0; a < A; a += stride) {
        const float t = angles[a];
        const int j = angle_index[A + a];
        int c = 0;
#pragma unroll
        for (int k = 0; k < HID; ++k) {
            const bool pos = w1[k] > 0.f;
            const bool on  = fmaf(t, w1[k], b1[k]) > 0.f;
            c += (pos ? on : !on) ? 1 : 0;
        }
        if (c - c0 >= PBIN) {
            float h[HID];
#pragma unroll
            for (int k = 0; k < HID; ++k) {
                float v = fmaf(t, w1[k], b1[k]);
                h[k] = v > 0.f ? v : 0.f;
            }
            for (int o = 0; o < OC; ++o) {
                float s = ab2[o];
#pragma unroll
                for (int k = 0; k < HID; ++k) s = fmaf(h[k], aW2[k * OC + o], s);
                unsafeAtomicAdd(out + (size_t)j * OC + o, s);
            }
        }
    }
}

// ---------------------------------------------------------------------------
// Edge branch v4: Z(E x 1056) @ W2r(1056 x 32) via mfma_f32_16x16x32_f16.
// Round-3 finding: Bf[33] (132 regs) exceeded the 96-VGPR allocation -> the
// compiler spilled B to memory, putting VMEM stalls in the K-loop and capping
// residency at ~1.5 blocks/CU. Fix: output-half (ot) is uniform per BLOCK
// (blockIdx parity); eW2/eb2 staged once into LDS as pre-swizzled f16
// [33 steps][16 ocols][32 k], row stride 40 f16 = 80 B (16-lane bank pattern
// is 2-way aliased = free per m136). K-loop reads B via one ds_read_b128 --
// no VMEM in the loop; VGPR drops to ~64; LDS 42.24 KB -> 3 blocks/CU
// (12 waves/CU, 2x round-3 residency).
// Fragment layouts (m89-verified): A[m=lane&15][k=q*8+j],
// B[k=q*8+j][n=lane&15], C/D[row=q*4+r][col=lane&15].
// ---------------------------------------------------------------------------
__global__ __launch_bounds__(256) void edge_kernel(
    const float* __restrict__ x, const int* __restrict__ edge_index,
    const float* __restrict__ edge_attr,
    const float* __restrict__ eW1, const float* __restrict__ eb1,
    const float* __restrict__ eW2, const float* __restrict__ eb2,
    float* __restrict__ out, int E)
{
    // [33][16][40] f16; only [..][..][0..31] used, 40-stride for bank spread
    __shared__ __align__(16) _Float16 Blds[33 * 16 * 40];

    const int tid  = threadIdx.x;
    const int lane = tid & 63;
    const int wib  = tid >> 6;
    const int ot   = blockIdx.x & 1;        // output half: block-uniform
    const int q    = lane >> 4;
    const int l15  = lane & 15;
    const int ocol = ot * 16 + l15;

    // --- stage B once: Blds[s][c][k] = eW2[s*1024 + k*32 + ot*16 + c] ------
    // idx = s*512 + c*32 + k : consecutive tid -> consecutive k (same line
    // group in LDS, 2B writes, 2-way bank aliasing = free)
    for (int idx = tid; idx < 33 * 512; idx += 256) {
        const int s = idx >> 9;
        const int c = (idx >> 5) & 15;
        const int k = idx & 31;
        const float v = (s < 32) ? eW2[s * 1024 + k * 32 + ot * 16 + c]
                                 : eb2[k * 32 + ot * 16 + c];
        Blds[(s * 16 + c) * 40 + k] = (_Float16)v;
    }
    __syncthreads();

    // this lane's B-fragment base: Blds[s][l15][q*8 .. q*8+7] (16B aligned)
    const _Float16* Bw = Blds + l15 * 40 + q * 8;

    const int numTiles = (E + 15) >> 4;
    const int tile0    = (blockIdx.x >> 1) * 4 + wib;
    const int tstride  = (gridDim.x >> 1) * 4;

    for (int tile = tile0; tile < numTiles; tile += tstride) {
        const int e16 = tile << 4;
        const int eA  = e16 + l15;
        const bool va = (eA < E);
        const int eAc = va ? eA : 0;

        // issue independent loads early: scatter dsts + t + col
        const int ebase = e16 + q * 4;
        int dsts[4];
#pragma unroll
        for (int r = 0; r < 4; ++r) {
            const int er = ebase + r;
            dsts[r] = (er < E) ? edge_index[er] : -1;
        }
        const float t  = va ? edge_attr[eAc] : 0.f;
        const int col  = va ? edge_index[E + eAc] : 0;

        const float* xp = x + (size_t)col * IC + q * 8;
        const float4 xlo = *(const float4*)(xp);
        const float4 xhi = *(const float4*)(xp + 4);

        // convert x fragment to f16 once per tile
        half8 xh;
        xh[0] = f2h(xlo.x); xh[1] = f2h(xlo.y);
        xh[2] = f2h(xlo.z); xh[3] = f2h(xlo.w);
        xh[4] = f2h(xhi.x); xh[5] = f2h(xhi.y);
        xh[6] = f2h(xhi.z); xh[7] = f2h(xhi.w);

        f32x4 acc = {0.f, 0.f, 0.f, 0.f};
#pragma unroll
        for (int s = 0; s < 32; ++s) {
            float hs = fmaf(t, eW1[s], eb1[s]);
            hs = hs > 0.f ? hs : 0.f;
            const _Float16 hh = f2h(hs);
            half8 hv = {hh, hh, hh, hh, hh, hh, hh, hh};
            half8 a = xh * hv;                          // 4x v_pk_mul_f16
            const half8 b = *(const half8*)(Bw + s * (16 * 40));  // ds_read_b128
            acc = __builtin_amdgcn_mfma_f32_16x16x32_f16(a, b, acc, 0, 0, 0);
        }
        {   // bias K-step (h == 1): adds sum_i x_i * eb2[i*32+o]
            const half8 b = *(const half8*)(Bw + 32 * (16 * 40));
            acc = __builtin_amdgcn_mfma_f32_16x16x32_f16(xh, b, acc, 0, 0, 0);
        }

        // scatter: C row r holds edge e16 + q*4 + r, col = ocol
#pragma unroll
        for (int r = 0; r < 4; ++r) {
            if (dsts[r] >= 0)
                unsafeAtomicAdd(out + (size_t)dsts[r] * OC + ocol, acc[r]);
        }
    }
}

// ---------------------------------------------------------------------------
extern "C" void kernel_launch(void* const* d_in, const int* in_sizes, int n_in,
                              void* d_out, int out_size, void* d_ws, size_t ws_size,
                              hipStream_t stream)
{
    const float* x          = (const float*)d_in[0];
    const int*   edge_index = (const int*)d_in[1];
    const float* edge_attr  = (const float*)d_in[2];
    const int*   angle_index= (const int*)d_in[3];
    const float* angles     = (const float*)d_in[4];
    const float* eW1        = (const float*)d_in[5];
    const float* eb1        = (const float*)d_in[6];
    const float* eW2        = (const float*)d_in[7];
    const float* eb2        = (const float*)d_in[8];
    const float* aW1        = (const float*)d_in[9];
    const float* ab1        = (const float*)d_in[10];
    const float* aW2        = (const float*)d_in[11];
    const float* ab2        = (const float*)d_in[12];
    float* out = (float*)d_out;
    (void)d_ws; (void)ws_size;   // no workspace needed: bins live in out[]

    const int E = in_sizes[1] / 2;
    const int A = in_sizes[3] / 3;
    const int N = in_sizes[0] / IC;

    // 1) clear out (doubles as clearing the u64 binning cells)
    const int zblocks = (out_size / 4 + 255) / 256;
    zero_kernel<<<zblocks, 256, 0, stream>>>(out, out_size);

    // 2) bin angles: 1 u64 atomic per angle into out-as-cells
    const int sblocks = (A + 255) / 256;
    angle_scatter<<<sblocks, 256, 0, stream>>>(angles, angle_index,
                                               aW1, ab1, (u64*)out, A);

    // 3) decode cells -> exact fp32 angle contribution, overwrite out rows
    const int gblocks = (N + 7) / 8;
    angle_gather<<<gblocks, 256, 0, stream>>>(out, aW1, ab1, aW2, ab2, N);

    // 4) expected-empty fixup for >PBIN realized pieces (uniform early-exit)
    angle_fixup<<<sblocks, 256, 0, stream>>>(angles, angle_index,
                                             aW1, ab1, aW2, ab2, out, A);

    // 5) edge branch accumulates on top via atomics
    edge_kernel<<<1024, 256, 0, stream>>>(x, edge_index, edge_attr,
                                          eW1, eb1, eW2, eb2, out, E);
}

// Round 5
// 191.856 us; speedup vs baseline: 1.1035x; 1.1035x over previous
//
#include <hip/hip_runtime.h>
#include <hip/hip_bf16.h>
#include <stdint.h>

#define IC 32
#define OC 32
#define HID 32

// Angle binning: per node, PBIN u64 cells of (count << TSH | sum of t*2^20),
// stored IN-PLACE in the output buffer (one node row = 32 floats = 16 u64).
// count field: 20 bits (max 1M >= A=400k). t-sum: 44 bits (A*2^20 < 2^39).
#define PBIN 16
#define TSH 44
#define TSCALE 1048576.0f   // 2^20

typedef __attribute__((ext_vector_type(8))) _Float16 half8;
typedef __attribute__((ext_vector_type(4))) float f32x4;
typedef unsigned long long u64;

static __device__ __forceinline__ _Float16 f2h(float f) { return (_Float16)f; }

// ---------------------------------------------------------------------------
// Zero-init output (also clears the in-place binning cells)
// ---------------------------------------------------------------------------
__global__ void zero_kernel(float* __restrict__ out, int n) {
    int i = (blockIdx.x * blockDim.x + threadIdx.x) * 4;
    if (i + 3 < n) {
        *(float4*)(out + i) = make_float4(0.f, 0.f, 0.f, 0.f);
    } else {
        for (int k = i; k < n; ++k) out[k] = 0.f;
    }
}

// ---------------------------------------------------------------------------
// Angle stage 1: classify each angle onto its linear piece of
//   feat(t) = relu(t*aW1 + ab1) @ aW2 + ab2   (piecewise-linear in scalar t)
// Piece id c(t) = # hinges in their t->+inf state (monotone in t; equal c
// => identical relu mask => feat linear over the group). Accumulate
// (count, sum-of-t) per (node, piece) with ONE u64 atomic per angle,
// directly into out[] reinterpreted as u64 cells (cleared by zero_kernel).
// ---------------------------------------------------------------------------
__global__ __launch_bounds__(256) void angle_scatter(
    const float* __restrict__ angles, const int* __restrict__ angle_index,
    const float* __restrict__ aW1, const float* __restrict__ ab1,
    u64* __restrict__ cells, int A)
{
    float w1[HID], b1[HID];
#pragma unroll
    for (int k = 0; k < HID; ++k) { w1[k] = aW1[k]; b1[k] = ab1[k]; }

    int i0 = blockIdx.x * blockDim.x + threadIdx.x;
    int stride = gridDim.x * blockDim.x;
    for (int a = i0; a < A; a += stride) {
        const float t = angles[a];
        const int j = angle_index[A + a];   // center node
        int c = 0, c0 = 0;
#pragma unroll
        for (int k = 0; k < HID; ++k) {
            const bool pos = w1[k] > 0.f;
            const bool on  = fmaf(t, w1[k], b1[k]) > 0.f;
            const bool on0 = b1[k] > 0.f;
            c  += (pos ? on  : !on ) ? 1 : 0;
            c0 += (pos ? on0 : !on0) ? 1 : 0;
        }
        const int cc = c - c0;
        if ((unsigned)cc < (unsigned)PBIN) {
            const u64 enc = ((u64)1 << TSH) | (u64)(unsigned)(t * TSCALE);
            atomicAdd(cells + (size_t)j * PBIN + cc, enc);
        }
        // cc >= PBIN (requires >16 realized pieces) handled by angle_fixup
    }
}

// ---------------------------------------------------------------------------
// Angle stage 2: per node, decode its 16 cells and evaluate
//   sum_pieces cnt * feat(tsum/cnt)    (exact: feat linear on each piece,
//   and the group mean stays inside the piece interval).
// 2 nodes per wave (32 lanes = 32 output channels). Reads the node's own
// row as u64, then OVERWRITES it with the fp32 result.
// ---------------------------------------------------------------------------
__global__ __launch_bounds__(256) void angle_gather(
    float* __restrict__ out,
    const float* __restrict__ aW1, const float* __restrict__ ab1,
    const float* __restrict__ aW2, const float* __restrict__ ab2,
    int N)
{
    const int lane = threadIdx.x & 63;
    const int o    = lane & 31;
    const int half = lane >> 5;
    const int wib  = threadIdx.x >> 6;
    const int gw   = blockIdx.x * (blockDim.x >> 6) + wib;
    const int nodesPerIter = gridDim.x * (blockDim.x >> 6) * 2;

    float w1[HID], b1[HID], w2[HID];
#pragma unroll
    for (int k = 0; k < HID; ++k) {
        w1[k] = aW1[k];
        b1[k] = ab1[k];
        w2[k] = aW2[k * OC + o];
    }
    const float bias = ab2[o];

    for (int j = gw * 2 + half; j < N; j += nodesPerIter) {
        const u64* cj = (const u64*)out + (size_t)j * PBIN;
        float acc = 0.f, tot = 0.f;
#pragma unroll
        for (int cc = 0; cc < PBIN; ++cc) {
            const u64 v = cj[cc];
            if (v) {
                const float n  = (float)(unsigned)(v >> TSH);
                const float ts = (float)(v & (((u64)1 << TSH) - 1)) * (1.f / TSCALE);
                const float tb = ts / n;
                float s = 0.f;
#pragma unroll
                for (int k = 0; k < HID; ++k) {
                    float h = fmaf(tb, w1[k], b1[k]);
                    h = h > 0.f ? h : 0.f;
                    s = fmaf(h, w2[k], s);
                }
                acc = fmaf(n, s, acc);
                tot += n;
            }
        }
        out[(size_t)j * OC + o] = fmaf(tot, bias, acc);
    }
}

// ---------------------------------------------------------------------------
// Fixup for angles whose piece index exceeds PBIN (only possible if the
// weight draw realizes >16 pieces on t in [0,1); expected ZERO work --
// uniform early-exit). Runs AFTER gather, adds exact feat via atomics.
// ---------------------------------------------------------------------------
__global__ __launch_bounds__(256) void angle_fixup(
    const float* __restrict__ angles, const int* __restrict__ angle_index,
    const float* __restrict__ aW1, const float* __restrict__ ab1,
    const float* __restrict__ aW2, const float* __restrict__ ab2,
    float* __restrict__ out, int A)
{
    float w1[HID], b1[HID];
#pragma unroll
    for (int k = 0; k < HID; ++k) { w1[k] = aW1[k]; b1[k] = ab1[k]; }

    int c0 = 0, c1 = 0;
#pragma unroll
    for (int k = 0; k < HID; ++k) {
        const bool pos = w1[k] > 0.f;
        const bool f0 = pos ? (b1[k] > 0.f) : !(b1[k] > 0.f);
        const bool f1 = pos ? ((w1[k] + b1[k]) > 0.f) : !((w1[k] + b1[k]) > 0.f);
        c0 += f0 ? 1 : 0;
        c1 += f1 ? 1 : 0;
    }
    if (c1 - c0 + 1 <= PBIN) return;   // uniform: no overflow possible

    int i0 = blockIdx.x * blockDim.x + threadIdx.x;
    int stride = gridDim.x * blockDim.x;
    for (int a = i0; a < A; a += stride) {
        const float t = angles[a];
        const int j = angle_index[A + a];
        int c = 0;
#pragma unroll
        for (int k = 0; k < HID; ++k) {
            const bool pos = w1[k] > 0.f;
            const bool on  = fmaf(t, w1[k], b1[k]) > 0.f;
            c += (pos ? on : !on) ? 1 : 0;
        }
        if (c - c0 >= PBIN) {
            float h[HID];
#pragma unroll
            for (int k = 0; k < HID; ++k) {
                float v = fmaf(t, w1[k], b1[k]);
                h[k] = v > 0.f ? v : 0.f;
            }
            for (int o = 0; o < OC; ++o) {
                float s = ab2[o];
#pragma unroll
                for (int k = 0; k < HID; ++k) s = fmaf(h[k], aW2[k * OC + o], s);
                unsafeAtomicAdd(out + (size_t)j * OC + o, s);
            }
        }
    }
}

// ---------------------------------------------------------------------------
// Edge branch v5 = R3 structure + 2-way tile interleave.
//   Z(E x 1056) @ W2r(1056 x 32) via mfma_f32_16x16x32_f16, scatter-atomic.
// R4 post-mortem: B-frags live in AGPRs (CSV VGPR=96 excludes them); total
// footprint ~232-256 regs -> pinned at 2 waves/SIMD regardless of grid.
// Therefore per-wave serial chain (edge_index -> x[col] -> cvt -> 33
// DEPENDENT MFMAs) is the bottleneck. Fix: process two tiles (t, t+tstride)
// per iteration -- two independent gather chains + alternating MFMA issue
// fills each MFMA's dependent-latency bubble with the sibling tile's op.
// Wave-level half split (ot = gwave&1) keeps both halves of a tile in the
// same block => x L2 reuse (R4's block-level split cost +7.7MB FETCH).
// ---------------------------------------------------------------------------
__global__ __launch_bounds__(256) void edge_kernel(
    const float* __restrict__ x, const int* __restrict__ edge_index,
    const float* __restrict__ edge_attr,
    const float* __restrict__ eW1, const float* __restrict__ eb1,
    const float* __restrict__ eW2, const float* __restrict__ eb2,
    float* __restrict__ out, int E)
{
    const int tid   = threadIdx.x;
    const int lane  = tid & 63;
    const int gwave = blockIdx.x * 4 + (tid >> 6);
    const int ot    = gwave & 1;            // which 16-wide output tile
    const int tile0 = gwave >> 1;
    const int tstride = (gridDim.x * 4) >> 1;
    const int q     = lane >> 4;
    const int l15   = lane & 15;
    const int ocol  = ot * 16 + l15;

    // --- load B fragments once (AGPR-resident across all edge tiles) ------
    half8 Bf[33];
#pragma unroll
    for (int s = 0; s < 32; ++s) {
        half8 b;
#pragma unroll
        for (int j = 0; j < 8; ++j)
            b[j] = f2h(eW2[s * 1024 + (q * 8 + j) * 32 + ocol]);
        Bf[s] = b;
    }
    {
        half8 b;
#pragma unroll
        for (int j = 0; j < 8; ++j)
            b[j] = f2h(eb2[(q * 8 + j) * 32 + ocol]);
        Bf[32] = b;
    }

    const int numTiles = (E + 15) >> 4;

    for (int tile = tile0; tile < numTiles; tile += 2 * tstride) {
        const int tA = tile;
        const int tB = tile + tstride;
        const bool hasB = (tB < numTiles);

        // ---- tile A inputs ----
        const int eA  = (tA << 4) + l15;
        const bool va = (eA < E);
        const int eAc = va ? eA : 0;
        const float ta = va ? edge_attr[eAc] : 0.f;
        const int colA = va ? edge_index[E + eAc] : 0;

        // ---- tile B inputs (independent chain, issued back-to-back) ----
        const int eB  = (tB << 4) + l15;
        const bool vb = hasB && (eB < E);
        const int eBc = vb ? eB : 0;
        const float tb = vb ? edge_attr[eBc] : 0.f;
        const int colB = vb ? edge_index[E + eBc] : 0;

        const float* xpA = x + (size_t)colA * IC + q * 8;
        const float4 xloA = *(const float4*)(xpA);
        const float4 xhiA = *(const float4*)(xpA + 4);
        const float* xpB = x + (size_t)colB * IC + q * 8;
        const float4 xloB = *(const float4*)(xpB);
        const float4 xhiB = *(const float4*)(xpB + 4);

        // scatter row indices (hoisted; latency hides under MFMA loop)
        int dstsA[4], dstsB[4];
        const int ebaseA = (tA << 4) + q * 4;
        const int ebaseB = (tB << 4) + q * 4;
#pragma unroll
        for (int r = 0; r < 4; ++r) {
            const int erA = ebaseA + r;
            dstsA[r] = (erA < E) ? edge_index[erA] : -1;
            const int erB = ebaseB + r;
            dstsB[r] = (hasB && erB < E) ? edge_index[erB] : -1;
        }

        half8 xhA, xhB;
        xhA[0] = f2h(xloA.x); xhA[1] = f2h(xloA.y);
        xhA[2] = f2h(xloA.z); xhA[3] = f2h(xloA.w);
        xhA[4] = f2h(xhiA.x); xhA[5] = f2h(xhiA.y);
        xhA[6] = f2h(xhiA.z); xhA[7] = f2h(xhiA.w);
        xhB[0] = f2h(xloB.x); xhB[1] = f2h(xloB.y);
        xhB[2] = f2h(xloB.z); xhB[3] = f2h(xloB.w);
        xhB[4] = f2h(xhiB.x); xhB[5] = f2h(xhiB.y);
        xhB[6] = f2h(xhiB.z); xhB[7] = f2h(xhiB.w);

        f32x4 accA = {0.f, 0.f, 0.f, 0.f};
        f32x4 accB = {0.f, 0.f, 0.f, 0.f};
#pragma unroll
        for (int s = 0; s < 32; ++s) {
            const float w1s = eW1[s], b1s = eb1[s];
            float hsA = fmaf(ta, w1s, b1s);
            hsA = hsA > 0.f ? hsA : 0.f;
            float hsB = fmaf(tb, w1s, b1s);
            hsB = hsB > 0.f ? hsB : 0.f;
            const _Float16 hA = f2h(hsA);
            const _Float16 hB = f2h(hsB);
            half8 hvA = {hA, hA, hA, hA, hA, hA, hA, hA};
            half8 hvB = {hB, hB, hB, hB, hB, hB, hB, hB};
            half8 aA = xhA * hvA;           // 4x v_pk_mul_f16 each
            half8 aB = xhB * hvB;
            // two independent acc chains: back-to-back issue fills latency
            accA = __builtin_amdgcn_mfma_f32_16x16x32_f16(aA, Bf[s], accA, 0, 0, 0);
            accB = __builtin_amdgcn_mfma_f32_16x16x32_f16(aB, Bf[s], accB, 0, 0, 0);
        }
        {   // bias K-step (h == 1): adds sum_i x_i * eb2[i*32+o]
            accA = __builtin_amdgcn_mfma_f32_16x16x32_f16(xhA, Bf[32], accA, 0, 0, 0);
            accB = __builtin_amdgcn_mfma_f32_16x16x32_f16(xhB, Bf[32], accB, 0, 0, 0);
        }

        // scatter: C row r holds edge e16 + q*4 + r, col = ocol
#pragma unroll
        for (int r = 0; r < 4; ++r) {
            if (dstsA[r] >= 0)
                unsafeAtomicAdd(out + (size_t)dstsA[r] * OC + ocol, accA[r]);
        }
#pragma unroll
        for (int r = 0; r < 4; ++r) {
            if (dstsB[r] >= 0)
                unsafeAtomicAdd(out + (size_t)dstsB[r] * OC + ocol, accB[r]);
        }
    }
}

// ---------------------------------------------------------------------------
extern "C" void kernel_launch(void* const* d_in, const int* in_sizes, int n_in,
                              void* d_out, int out_size, void* d_ws, size_t ws_size,
                              hipStream_t stream)
{
    const float* x          = (const float*)d_in[0];
    const int*   edge_index = (const int*)d_in[1];
    const float* edge_attr  = (const float*)d_in[2];
    const int*   angle_index= (const int*)d_in[3];
    const float* angles     = (const float*)d_in[4];
    const float* eW1        = (const float*)d_in[5];
    const float* eb1        = (const float*)d_in[6];
    const float* eW2        = (const float*)d_in[7];
    const float* eb2        = (const float*)d_in[8];
    const float* aW1        = (const float*)d_in[9];
    const float* ab1        = (const float*)d_in[10];
    const float* aW2        = (const float*)d_in[11];
    const float* ab2        = (const float*)d_in[12];
    float* out = (float*)d_out;
    (void)d_ws; (void)ws_size;   // no workspace needed: bins live in out[]

    const int E = in_sizes[1] / 2;
    const int A = in_sizes[3] / 3;
    const int N = in_sizes[0] / IC;

    // 1) clear out (doubles as clearing the u64 binning cells)
    const int zblocks = (out_size / 4 + 255) / 256;
    zero_kernel<<<zblocks, 256, 0, stream>>>(out, out_size);

    // 2) bin angles: 1 u64 atomic per angle into out-as-cells
    const int sblocks = (A + 255) / 256;
    angle_scatter<<<sblocks, 256, 0, stream>>>(angles, angle_index,
                                               aW1, ab1, (u64*)out, A);

    // 3) decode cells -> exact fp32 angle contribution, overwrite out rows
    const int gblocks = (N + 7) / 8;
    angle_gather<<<gblocks, 256, 0, stream>>>(out, aW1, ab1, aW2, ab2, N);

    // 4) expected-empty fixup for >PBIN realized pieces (uniform early-exit)
    angle_fixup<<<sblocks, 256, 0, stream>>>(angles, angle_index,
                                             aW1, ab1, aW2, ab2, out, A);

    // 5) edge branch accumulates on top via atomics
    edge_kernel<<<512, 256, 0, stream>>>(x, edge_index, edge_attr,
                                         eW1, eb1, eW2, eb2, out, E);
}

// Round 6
// 166.780 us; speedup vs baseline: 1.2694x; 1.1504x over previous
//
#include <hip/hip_runtime.h>
#include <hip/hip_bf16.h>
#include <stdint.h>

#define IC 32
#define OC 32
#define HID 32

// Angle binning: per node, PBIN u64 cells of (count << TSH | sum of t*2^20),
// stored IN-PLACE in the output buffer (one node row = 32 floats = 16 u64).
// count field: 20 bits (max 1M >= A=400k). t-sum: 44 bits (A*2^20 < 2^39).
#define PBIN 16
#define TSH 44
#define TSCALE 1048576.0f   // 2^20

typedef __attribute__((ext_vector_type(8))) _Float16 half8;
typedef __attribute__((ext_vector_type(4))) float f32x4;
typedef unsigned long long u64;

static __device__ __forceinline__ _Float16 f2h(float f) { return (_Float16)f; }

// ---------------------------------------------------------------------------
// Zero-init output (also clears the in-place binning cells)
// ---------------------------------------------------------------------------
__global__ void zero_kernel(float* __restrict__ out, int n) {
    int i = (blockIdx.x * blockDim.x + threadIdx.x) * 4;
    if (i + 3 < n) {
        *(float4*)(out + i) = make_float4(0.f, 0.f, 0.f, 0.f);
    } else {
        for (int k = i; k < n; ++k) out[k] = 0.f;
    }
}

// ---------------------------------------------------------------------------
// Angle stage 1: classify each angle onto its linear piece of
//   feat(t) = relu(t*aW1 + ab1) @ aW2 + ab2   (piecewise-linear in scalar t)
// Piece id c(t) = # hinges in their t->+inf state (monotone in t; equal c
// => identical relu mask => feat linear over the group). Accumulate
// (count, sum-of-t) per (node, piece) with ONE u64 atomic per angle,
// directly into out[] reinterpreted as u64 cells (cleared by zero_kernel).
// Stored at cc = c - c(0), valid cc in [0, PBIN); overflow -> angle_fixup.
// ---------------------------------------------------------------------------
__global__ __launch_bounds__(256) void angle_scatter(
    const float* __restrict__ angles, const int* __restrict__ angle_index,
    const float* __restrict__ aW1, const float* __restrict__ ab1,
    u64* __restrict__ cells, int A)
{
    float w1[HID], b1[HID];
#pragma unroll
    for (int k = 0; k < HID; ++k) { w1[k] = aW1[k]; b1[k] = ab1[k]; }

    int i0 = blockIdx.x * blockDim.x + threadIdx.x;
    int stride = gridDim.x * blockDim.x;
    for (int a = i0; a < A; a += stride) {
        const float t = angles[a];
        const int j = angle_index[A + a];   // center node
        int c = 0, c0 = 0;
#pragma unroll
        for (int k = 0; k < HID; ++k) {
            const bool pos = w1[k] > 0.f;
            const bool on  = fmaf(t, w1[k], b1[k]) > 0.f;
            const bool on0 = b1[k] > 0.f;
            c  += (pos ? on  : !on ) ? 1 : 0;
            c0 += (pos ? on0 : !on0) ? 1 : 0;
        }
        const int cc = c - c0;
        if ((unsigned)cc < (unsigned)PBIN) {
            const u64 enc = ((u64)1 << TSH) | (u64)(unsigned)(t * TSCALE);
            atomicAdd(cells + (size_t)j * PBIN + cc, enc);
        }
    }
}

// ---------------------------------------------------------------------------
// Angle stage 2 v2 (MFMA): per wave, 16 nodes. Lane (l15,q) builds A-frag
//   g[k] = sum_c n_c * relu(tb_c*w1[k]+b1[k])   (node base+l15, k=q*8..+7)
// so out[node][o] = sum_k g[k]*W2[k][o]  ==  two mfma_f32_16x16x32_f16
// (16 nodes x 16 channels each), exact piecewise-linear semantics, the n_c
// weighting folded into A. tot (angle count) broadcast via __shfl for the
// +tot*ab2[o] term. Cell loop runs only over the wave-uniform realized
// range [c0,c1] (~6 iters). Reads the node rows as u64 cells, then
// overwrites them -- safe: every store depends on the MFMA result, which
// depends on ALL lanes' cell reads (reads complete before writes).
// Replaces the old scalar gather: ~24x less VALU work per node.
// ---------------------------------------------------------------------------
__global__ __launch_bounds__(256) void angle_gather(
    float* __restrict__ out,
    const float* __restrict__ aW1, const float* __restrict__ ab1,
    const float* __restrict__ aW2, const float* __restrict__ ab2,
    int N)
{
    const int lane = threadIdx.x & 63;
    const int q    = lane >> 4;
    const int l15  = lane & 15;
    const int wib  = threadIdx.x >> 6;
    const int base = (blockIdx.x * 4 + wib) * 16;   // wave's first node
    if (base >= N) return;

    // per-lane k-slice of layer-1 params + wave-uniform realized piece range
    float w1s[8], b1s[8];
    int c0 = 0, c1 = 0;
#pragma unroll
    for (int k = 0; k < HID; ++k) {
        const float w = aW1[k], b = ab1[k];
        const bool pos = w > 0.f;
        const bool f0 = pos ? (b > 0.f) : !(b > 0.f);
        const bool f1 = pos ? ((w + b) > 0.f) : !((w + b) > 0.f);
        c0 += f0 ? 1 : 0;
        c1 += f1 ? 1 : 0;
        if ((k >> 3) == q) { w1s[k & 7] = w; b1s[k & 7] = b; }  // static idx
    }
    int npc = c1 - c0 + 1;
    if (npc > PBIN) npc = PBIN;   // cc >= PBIN handled by angle_fixup

    // B fragments for both output halves: B[k=q*8+j][n=l15]
    half8 Bf0, Bf1;
#pragma unroll
    for (int j = 0; j < 8; ++j) {
        Bf0[j] = f2h(aW2[(q * 8 + j) * OC + l15]);
        Bf1[j] = f2h(aW2[(q * 8 + j) * OC + 16 + l15]);
    }
    const float bias0 = ab2[l15];
    const float bias1 = ab2[16 + l15];

    // build A-frag for node base+l15 (4-way redundant across q: L1 hits)
    const int jn = base + l15;
    const bool vn = (jn < N);
    const u64* cj = (const u64*)out + (size_t)(vn ? jn : 0) * PBIN;
    float g[8] = {0.f, 0.f, 0.f, 0.f, 0.f, 0.f, 0.f, 0.f};
    float tot = 0.f;
    for (int cc = 0; cc < npc; ++cc) {
        const u64 v = vn ? cj[cc] : 0;
        if (v) {
            const float n  = (float)(unsigned)(v >> TSH);
            const float ts = (float)(v & (((u64)1 << TSH) - 1)) * (1.f / TSCALE);
            const float tb = ts / n;
#pragma unroll
            for (int k = 0; k < 8; ++k) {
                float h = fmaf(tb, w1s[k], b1s[k]);
                h = h > 0.f ? h : 0.f;
                g[k] = fmaf(n, h, g[k]);
            }
            tot += n;
        }
    }
    half8 a;
#pragma unroll
    for (int k = 0; k < 8; ++k) a[k] = f2h(g[k]);

    f32x4 acc0 = {0.f, 0.f, 0.f, 0.f};
    f32x4 acc1 = {0.f, 0.f, 0.f, 0.f};
    acc0 = __builtin_amdgcn_mfma_f32_16x16x32_f16(a, Bf0, acc0, 0, 0, 0);
    acc1 = __builtin_amdgcn_mfma_f32_16x16x32_f16(a, Bf1, acc1, 0, 0, 0);

    // D[row=q*4+r][col=l15]; row = node index within tile
#pragma unroll
    for (int r = 0; r < 4; ++r) {
        const int node = base + q * 4 + r;
        const float tr = __shfl(tot, q * 4 + r, 64);   // that node's count
        if (node < N) {
            out[(size_t)node * OC + l15]      = fmaf(tr, bias0, acc0[r]);
            out[(size_t)node * OC + 16 + l15] = fmaf(tr, bias1, acc1[r]);
        }
    }
}

// ---------------------------------------------------------------------------
// Fixup for angles whose piece index exceeds PBIN (only possible if the
// weight draw realizes >16 pieces on t in [0,1); expected ZERO work --
// uniform early-exit). Runs AFTER gather, adds exact feat via atomics.
// ---------------------------------------------------------------------------
__global__ __launch_bounds__(256) void angle_fixup(
    const float* __restrict__ angles, const int* __restrict__ angle_index,
    const float* __restrict__ aW1, const float* __restrict__ ab1,
    const float* __restrict__ aW2, const float* __restrict__ ab2,
    float* __restrict__ out, int A)
{
    float w1[HID], b1[HID];
#pragma unroll
    for (int k = 0; k < HID; ++k) { w1[k] = aW1[k]; b1[k] = ab1[k]; }

    int c0 = 0, c1 = 0;
#pragma unroll
    for (int k = 0; k < HID; ++k) {
        const bool pos = w1[k] > 0.f;
        const bool f0 = pos ? (b1[k] > 0.f) : !(b1[k] > 0.f);
        const bool f1 = pos ? ((w1[k] + b1[k]) > 0.f) : !((w1[k] + b1[k]) > 0.f);
        c0 += f0 ? 1 : 0;
        c1 += f1 ? 1 : 0;
    }
    if (c1 - c0 + 1 <= PBIN) return;   // uniform: no overflow possible

    int i0 = blockIdx.x * blockDim.x + threadIdx.x;
    int stride = gridDim.x * blockDim.x;
    for (int a = i0; a < A; a += stride) {
        const float t = angles[a];
        const int j = angle_index[A + a];
        int c = 0;
#pragma unroll
        for (int k = 0; k < HID; ++k) {
            const bool pos = w1[k] > 0.f;
            const bool on  = fmaf(t, w1[k], b1[k]) > 0.f;
            c += (pos ? on : !on) ? 1 : 0;
        }
        if (c - c0 >= PBIN) {
            float h[HID];
#pragma unroll
            for (int k = 0; k < HID; ++k) {
                float v = fmaf(t, w1[k], b1[k]);
                h[k] = v > 0.f ? v : 0.f;
            }
            for (int o = 0; o < OC; ++o) {
                float s = ab2[o];
#pragma unroll
                for (int k = 0; k < HID; ++k) s = fmaf(h[k], aW2[k * OC + o], s);
                unsafeAtomicAdd(out + (size_t)j * OC + o, s);
            }
        }
    }
}

// ---------------------------------------------------------------------------
// Edge branch v5 (unchanged from round 5 -- proven):
//   Z(E x 1056) @ W2r(1056 x 32) via mfma_f32_16x16x32_f16, scatter-atomic.
// B-frags AGPR-resident; 2-way tile interleave fills MFMA dependent-latency
// bubbles (two independent gather+MFMA chains per iteration). Wave-level
// half split keeps both halves of a tile in one block => x L2 reuse.
// ---------------------------------------------------------------------------
__global__ __launch_bounds__(256) void edge_kernel(
    const float* __restrict__ x, const int* __restrict__ edge_index,
    const float* __restrict__ edge_attr,
    const float* __restrict__ eW1, const float* __restrict__ eb1,
    const float* __restrict__ eW2, const float* __restrict__ eb2,
    float* __restrict__ out, int E)
{
    const int tid   = threadIdx.x;
    const int lane  = tid & 63;
    const int gwave = blockIdx.x * 4 + (tid >> 6);
    const int ot    = gwave & 1;            // which 16-wide output tile
    const int tile0 = gwave >> 1;
    const int tstride = (gridDim.x * 4) >> 1;
    const int q     = lane >> 4;
    const int l15   = lane & 15;
    const int ocol  = ot * 16 + l15;

    // --- load B fragments once (AGPR-resident across all edge tiles) ------
    half8 Bf[33];
#pragma unroll
    for (int s = 0; s < 32; ++s) {
        half8 b;
#pragma unroll
        for (int j = 0; j < 8; ++j)
            b[j] = f2h(eW2[s * 1024 + (q * 8 + j) * 32 + ocol]);
        Bf[s] = b;
    }
    {
        half8 b;
#pragma unroll
        for (int j = 0; j < 8; ++j)
            b[j] = f2h(eb2[(q * 8 + j) * 32 + ocol]);
        Bf[32] = b;
    }

    const int numTiles = (E + 15) >> 4;

    for (int tile = tile0; tile < numTiles; tile += 2 * tstride) {
        const int tA = tile;
        const int tB = tile + tstride;
        const bool hasB = (tB < numTiles);

        // ---- tile A inputs ----
        const int eA  = (tA << 4) + l15;
        const bool va = (eA < E);
        const int eAc = va ? eA : 0;
        const float ta = va ? edge_attr[eAc] : 0.f;
        const int colA = va ? edge_index[E + eAc] : 0;

        // ---- tile B inputs (independent chain, issued back-to-back) ----
        const int eB  = (tB << 4) + l15;
        const bool vb = hasB && (eB < E);
        const int eBc = vb ? eB : 0;
        const float tb = vb ? edge_attr[eBc] : 0.f;
        const int colB = vb ? edge_index[E + eBc] : 0;

        const float* xpA = x + (size_t)colA * IC + q * 8;
        const float4 xloA = *(const float4*)(xpA);
        const float4 xhiA = *(const float4*)(xpA + 4);
        const float* xpB = x + (size_t)colB * IC + q * 8;
        const float4 xloB = *(const float4*)(xpB);
        const float4 xhiB = *(const float4*)(xpB + 4);

        // scatter row indices (hoisted; latency hides under MFMA loop)
        int dstsA[4], dstsB[4];
        const int ebaseA = (tA << 4) + q * 4;
        const int ebaseB = (tB << 4) + q * 4;
#pragma unroll
        for (int r = 0; r < 4; ++r) {
            const int erA = ebaseA + r;
            dstsA[r] = (erA < E) ? edge_index[erA] : -1;
            const int erB = ebaseB + r;
            dstsB[r] = (hasB && erB < E) ? edge_index[erB] : -1;
        }

        half8 xhA, xhB;
        xhA[0] = f2h(xloA.x); xhA[1] = f2h(xloA.y);
        xhA[2] = f2h(xloA.z); xhA[3] = f2h(xloA.w);
        xhA[4] = f2h(xhiA.x); xhA[5] = f2h(xhiA.y);
        xhA[6] = f2h(xhiA.z); xhA[7] = f2h(xhiA.w);
        xhB[0] = f2h(xloB.x); xhB[1] = f2h(xloB.y);
        xhB[2] = f2h(xloB.z); xhB[3] = f2h(xloB.w);
        xhB[4] = f2h(xhiB.x); xhB[5] = f2h(xhiB.y);
        xhB[6] = f2h(xhiB.z); xhB[7] = f2h(xhiB.w);

        f32x4 accA = {0.f, 0.f, 0.f, 0.f};
        f32x4 accB = {0.f, 0.f, 0.f, 0.f};
#pragma unroll
        for (int s = 0; s < 32; ++s) {
            const float w1s = eW1[s], b1s = eb1[s];
            float hsA = fmaf(ta, w1s, b1s);
            hsA = hsA > 0.f ? hsA : 0.f;
            float hsB = fmaf(tb, w1s, b1s);
            hsB = hsB > 0.f ? hsB : 0.f;
            const _Float16 hA = f2h(hsA);
            const _Float16 hB = f2h(hsB);
            half8 hvA = {hA, hA, hA, hA, hA, hA, hA, hA};
            half8 hvB = {hB, hB, hB, hB, hB, hB, hB, hB};
            half8 aA = xhA * hvA;           // 4x v_pk_mul_f16 each
            half8 aB = xhB * hvB;
            // two independent acc chains: back-to-back issue fills latency
            accA = __builtin_amdgcn_mfma_f32_16x16x32_f16(aA, Bf[s], accA, 0, 0, 0);
            accB = __builtin_amdgcn_mfma_f32_16x16x32_f16(aB, Bf[s], accB, 0, 0, 0);
        }
        {   // bias K-step (h == 1): adds sum_i x_i * eb2[i*32+o]
            accA = __builtin_amdgcn_mfma_f32_16x16x32_f16(xhA, Bf[32], accA, 0, 0, 0);
            accB = __builtin_amdgcn_mfma_f32_16x16x32_f16(xhB, Bf[32], accB, 0, 0, 0);
        }

        // scatter: C row r holds edge e16 + q*4 + r, col = ocol
#pragma unroll
        for (int r = 0; r < 4; ++r) {
            if (dstsA[r] >= 0)
                unsafeAtomicAdd(out + (size_t)dstsA[r] * OC + ocol, accA[r]);
        }
#pragma unroll
        for (int r = 0; r < 4; ++r) {
            if (dstsB[r] >= 0)
                unsafeAtomicAdd(out + (size_t)dstsB[r] * OC + ocol, accB[r]);
        }
    }
}

// ---------------------------------------------------------------------------
extern "C" void kernel_launch(void* const* d_in, const int* in_sizes, int n_in,
                              void* d_out, int out_size, void* d_ws, size_t ws_size,
                              hipStream_t stream)
{
    const float* x          = (const float*)d_in[0];
    const int*   edge_index = (const int*)d_in[1];
    const float* edge_attr  = (const float*)d_in[2];
    const int*   angle_index= (const int*)d_in[3];
    const float* angles     = (const float*)d_in[4];
    const float* eW1        = (const float*)d_in[5];
    const float* eb1        = (const float*)d_in[6];
    const float* eW2        = (const float*)d_in[7];
    const float* eb2        = (const float*)d_in[8];
    const float* aW1        = (const float*)d_in[9];
    const float* ab1        = (const float*)d_in[10];
    const float* aW2        = (const float*)d_in[11];
    const float* ab2        = (const float*)d_in[12];
    float* out = (float*)d_out;
    (void)d_ws; (void)ws_size;   // no workspace needed: bins live in out[]

    const int E = in_sizes[1] / 2;
    const int A = in_sizes[3] / 3;
    const int N = in_sizes[0] / IC;

    // 1) clear out (doubles as clearing the u64 binning cells)
    const int zblocks = (out_size / 4 + 255) / 256;
    zero_kernel<<<zblocks, 256, 0, stream>>>(out, out_size);

    // 2) bin angles: 1 u64 atomic per angle into out-as-cells
    const int sblocks = (A + 255) / 256;
    angle_scatter<<<sblocks, 256, 0, stream>>>(angles, angle_index,
                                               aW1, ab1, (u64*)out, A);

    // 3) decode cells -> exact angle contribution via MFMA, overwrite rows
    const int gblocks = (N + 63) / 64;
    angle_gather<<<gblocks, 256, 0, stream>>>(out, aW1, ab1, aW2, ab2, N);

    // 4) expected-empty fixup for >PBIN realized pieces (uniform early-exit)
    angle_fixup<<<sblocks, 256, 0, stream>>>(angles, angle_index,
                                             aW1, ab1, aW2, ab2, out, A);

    // 5) edge branch accumulates on top via atomics
    edge_kernel<<<512, 256, 0, stream>>>(x, edge_index, edge_attr,
                                         eW1, eb1, eW2, eb2, out, E);
}

// Round 7
// 162.966 us; speedup vs baseline: 1.2991x; 1.0234x over previous
//
#include <hip/hip_runtime.h>
#include <hip/hip_bf16.h>
#include <stdint.h>

#define IC 32
#define OC 32
#define HID 32

// Angle binning: per node, PBIN u64 cells of (count << TSH | sum of t*2^20),
// stored IN-PLACE in the output buffer (one node row = 32 floats = 16 u64).
#define PBIN 16
#define TSH 44
#define TSCALE 1048576.0f   // 2^20

// Edge piecewise path: W(t) = M_c + t*K_c per linear piece c; fast path
// handles up to PBE realized pieces (LDS budget), remainder -> edge_fixup.
#define PBE 12

typedef __attribute__((ext_vector_type(8))) _Float16 half8;
typedef __attribute__((ext_vector_type(4))) float f32x4;
typedef unsigned long long u64;

static __device__ __forceinline__ _Float16 f2h(float f) { return (_Float16)f; }

// ---------------------------------------------------------------------------
// Device-global scratch (no d_ws dependence; rewritten in-stream each launch).
// g_MK: [cc][mat(M=0,K=1)][o][i] f16 piece matrices (transposed: i contiguous)
// g_ekn/g_akn: sorted realized hinge knots (pad = 1e30), g_npc: piece counts.
// ---------------------------------------------------------------------------
__device__ __align__(16) _Float16 g_MK[PBE * 2 * 32 * 32];
__device__ float g_ekn[16];
__device__ float g_akn[16];
__device__ int   g_npc[2];   // [0]=edge pieces, [1]=angle pieces

// ---------------------------------------------------------------------------
// Setup: block 0 writes sorted knots + piece counts for both MLPs (rank
// scatter -- no sort loop). All 96 blocks compute the PBE*2*32*32 entries of
// the edge piece matrices:  M_c = eb2 + sum_k on(k,c) b1k eW2k,
//                           K_c =       sum_k on(k,c) w1k eW2k.
// on(k,c): hinge k's relu state on piece c = (w>0) ? (on0||flip) : (on0&&!flip),
// flip = realized && rank_k < c  (the c smallest knots have flipped).
// ---------------------------------------------------------------------------
__global__ __launch_bounds__(256) void setup_kernel(
    const float* __restrict__ eW1, const float* __restrict__ eb1,
    const float* __restrict__ eW2, const float* __restrict__ eb2,
    const float* __restrict__ aW1, const float* __restrict__ ab1)
{
    __shared__ float ts_s[32];
    __shared__ int   rk_s[32];
    __shared__ int   re_s[32];
    const int tid = threadIdx.x;

    if (blockIdx.x == 0 && tid < 16) { g_ekn[tid] = 1e30f; g_akn[tid] = 1e30f; }

    if (tid < 32) {   // edge-MLP hinge table (every block, for mats)
        const int k = tid;
        const float w = eW1[k], b = eb1[k];
        const float ts = -b / w;
        const bool re = (w != 0.f) && (ts > 0.f) && (ts < 1.f);
        int rk = 0;
        for (int k2 = 0; k2 < 32; ++k2) {
            const float w2 = eW1[k2], b2 = eb1[k2];
            const float t2 = -b2 / w2;
            const bool re2 = (w2 != 0.f) && (t2 > 0.f) && (t2 < 1.f);
            rk += (re2 && (t2 < ts || (t2 == ts && k2 < k))) ? 1 : 0;
        }
        ts_s[k] = ts; rk_s[k] = rk; re_s[k] = re ? 1 : 0;
    }
    __syncthreads();

    if (blockIdx.x == 0) {
        if (tid < 32) {
            if (re_s[tid]) g_ekn[rk_s[tid]] = ts_s[tid];
            if (tid == 0) {
                int n = 0;
                for (int k = 0; k < 32; ++k) n += re_s[k];
                g_npc[0] = n + 1;
            }
        } else if (tid < 64) {   // angle-MLP knots
            const int k = tid - 32;
            const float w = aW1[k], b = ab1[k];
            const float ts = -b / w;
            const bool re = (w != 0.f) && (ts > 0.f) && (ts < 1.f);
            int rk = 0, nre = 0;
            for (int k2 = 0; k2 < 32; ++k2) {
                const float w2 = aW1[k2], b2 = ab1[k2];
                const float t2 = -b2 / w2;
                const bool re2 = (w2 != 0.f) && (t2 > 0.f) && (t2 < 1.f);
                nre += re2 ? 1 : 0;
                rk += (re2 && (t2 < ts || (t2 == ts && k2 < k))) ? 1 : 0;
            }
            if (re) g_akn[rk] = ts;
            if (k == 0) g_npc[1] = nre + 1;
        }
    }

    // ---- piece-matrix entries ----
    const int gid = blockIdx.x * blockDim.x + tid;
    if (gid < PBE * 2 * 32 * 32) {
        const int i   = gid & 31;
        const int o   = (gid >> 5) & 31;
        const int mat = (gid >> 10) & 1;
        const int cc  = gid >> 11;
        float acc = (mat == 0) ? eb2[i * 32 + o] : 0.f;
        for (int k = 0; k < 32; ++k) {
            const bool flip = re_s[k] && (rk_s[k] < cc);
            const float w = eW1[k], b = eb1[k];
            const bool on0 = b > 0.f;
            const bool on = (w > 0.f) ? (on0 || flip) : (on0 && !flip);
            if (on) acc = fmaf((mat == 0 ? b : w), eW2[k * 1024 + i * 32 + o], acc);
        }
        g_MK[((cc * 2 + mat) * 32 + o) * 32 + i] = (_Float16)acc;
    }
}

// ---------------------------------------------------------------------------
// Zero-init output (also clears the in-place binning cells)
// ---------------------------------------------------------------------------
__global__ void zero_kernel(float* __restrict__ out, int n) {
    int i = (blockIdx.x * blockDim.x + threadIdx.x) * 4;
    if (i + 3 < n) {
        *(float4*)(out + i) = make_float4(0.f, 0.f, 0.f, 0.f);
    } else {
        for (int k = i; k < n; ++k) out[k] = 0.f;
    }
}

// ---------------------------------------------------------------------------
// Angle stage 1: piece id cc = #realized knots <= t (== old flip-count),
// via 16 register compares against the sorted knot table. One u64 atomic
// per angle into out-as-cells. cc >= PBIN (npc_a > 16) -> angle_fixup.
// ---------------------------------------------------------------------------
__global__ __launch_bounds__(256) void angle_scatter(
    const float* __restrict__ angles, const int* __restrict__ angle_index,
    u64* __restrict__ cells, int A)
{
    float kn[16];
#pragma unroll
    for (int j = 0; j < 16; ++j) kn[j] = g_akn[j];

    int i0 = blockIdx.x * blockDim.x + threadIdx.x;
    int stride = gridDim.x * blockDim.x;
    for (int a = i0; a < A; a += stride) {
        const float t = angles[a];
        const int j = angle_index[A + a];   // center node
        int cc = 0;
#pragma unroll
        for (int jj = 0; jj < 16; ++jj) cc += (t >= kn[jj]) ? 1 : 0;
        if ((unsigned)cc < (unsigned)PBIN) {
            const u64 enc = ((u64)1 << TSH) | (u64)(unsigned)(t * TSCALE);
            atomicAdd(cells + (size_t)j * PBIN + cc, enc);
        }
    }
}

// ---------------------------------------------------------------------------
// Angle stage 2 (MFMA, proven in round 6): per wave 16 nodes; lane (l15,q)
// builds g[k] = sum_c n_c*relu(tb_c*w1k+b1k); two mfma_f32_16x16x32_f16
// produce all 32 channels; overwrites the node rows (exact piecewise).
// ---------------------------------------------------------------------------
__global__ __launch_bounds__(256) void angle_gather(
    float* __restrict__ out,
    const float* __restrict__ aW1, const float* __restrict__ ab1,
    const float* __restrict__ aW2, const float* __restrict__ ab2,
    int N)
{
    const int lane = threadIdx.x & 63;
    const int q    = lane >> 4;
    const int l15  = lane & 15;
    const int wib  = threadIdx.x >> 6;
    const int base = (blockIdx.x * 4 + wib) * 16;   // wave's first node
    if (base >= N) return;

    float w1s[8], b1s[8];
    int c0 = 0, c1 = 0;
#pragma unroll
    for (int k = 0; k < HID; ++k) {
        const float w = aW1[k], b = ab1[k];
        const bool pos = w > 0.f;
        const bool f0 = pos ? (b > 0.f) : !(b > 0.f);
        const bool f1 = pos ? ((w + b) > 0.f) : !((w + b) > 0.f);
        c0 += f0 ? 1 : 0;
        c1 += f1 ? 1 : 0;
        if ((k >> 3) == q) { w1s[k & 7] = w; b1s[k & 7] = b; }
    }
    int npc = c1 - c0 + 1;
    if (npc > PBIN) npc = PBIN;

    half8 Bf0, Bf1;
#pragma unroll
    for (int j = 0; j < 8; ++j) {
        Bf0[j] = f2h(aW2[(q * 8 + j) * OC + l15]);
        Bf1[j] = f2h(aW2[(q * 8 + j) * OC + 16 + l15]);
    }
    const float bias0 = ab2[l15];
    const float bias1 = ab2[16 + l15];

    const int jn = base + l15;
    const bool vn = (jn < N);
    const u64* cj = (const u64*)out + (size_t)(vn ? jn : 0) * PBIN;
    float g[8] = {0.f, 0.f, 0.f, 0.f, 0.f, 0.f, 0.f, 0.f};
    float tot = 0.f;
    for (int cc = 0; cc < npc; ++cc) {
        const u64 v = vn ? cj[cc] : 0;
        if (v) {
            const float n  = (float)(unsigned)(v >> TSH);
            const float ts = (float)(v & (((u64)1 << TSH) - 1)) * (1.f / TSCALE);
            const float tb = ts / n;
#pragma unroll
            for (int k = 0; k < 8; ++k) {
                float h = fmaf(tb, w1s[k], b1s[k]);
                h = h > 0.f ? h : 0.f;
                g[k] = fmaf(n, h, g[k]);
            }
            tot += n;
        }
    }
    half8 a;
#pragma unroll
    for (int k = 0; k < 8; ++k) a[k] = f2h(g[k]);

    f32x4 acc0 = {0.f, 0.f, 0.f, 0.f};
    f32x4 acc1 = {0.f, 0.f, 0.f, 0.f};
    acc0 = __builtin_amdgcn_mfma_f32_16x16x32_f16(a, Bf0, acc0, 0, 0, 0);
    acc1 = __builtin_amdgcn_mfma_f32_16x16x32_f16(a, Bf1, acc1, 0, 0, 0);

#pragma unroll
    for (int r = 0; r < 4; ++r) {
        const int node = base + q * 4 + r;
        const float tr = __shfl(tot, q * 4 + r, 64);
        if (node < N) {
            out[(size_t)node * OC + l15]      = fmaf(tr, bias0, acc0[r]);
            out[(size_t)node * OC + 16 + l15] = fmaf(tr, bias1, acc1[r]);
        }
    }
}

// ---------------------------------------------------------------------------
// Angle fixup: angles with piece index >= PBIN (only if npc_a > 16).
// Uniform early-exit; exact scalar path with atomics.
// ---------------------------------------------------------------------------
__global__ __launch_bounds__(256) void angle_fixup(
    const float* __restrict__ angles, const int* __restrict__ angle_index,
    const float* __restrict__ aW1, const float* __restrict__ ab1,
    const float* __restrict__ aW2, const float* __restrict__ ab2,
    float* __restrict__ out, int A)
{
    if (g_npc[1] <= PBIN) return;

    float w1[HID], b1[HID];
#pragma unroll
    for (int k = 0; k < HID; ++k) { w1[k] = aW1[k]; b1[k] = ab1[k]; }
    const float kn15 = g_akn[15];

    int i0 = blockIdx.x * blockDim.x + threadIdx.x;
    int stride = gridDim.x * blockDim.x;
    for (int a = i0; a < A; a += stride) {
        const float t = angles[a];
        if (t < kn15) continue;   // cc <= 15 handled by scatter/gather
        const int j = angle_index[A + a];
        float h[HID];
#pragma unroll
        for (int k = 0; k < HID; ++k) {
            float v = fmaf(t, w1[k], b1[k]);
            h[k] = v > 0.f ? v : 0.f;
        }
        for (int o = 0; o < OC; ++o) {
            float s = ab2[o];
#pragma unroll
            for (int k = 0; k < HID; ++k) s = fmaf(h[k], aW2[k * OC + o], s);
            unsafeAtomicAdd(out + (size_t)j * OC + o, s);
        }
    }
}

// ---------------------------------------------------------------------------
// Edge branch v6 (piecewise-linear): msg_e = x[col]*M_c + t*(x[col]*K_c)
// with c = piece(t_e). K-dim collapses 1056 -> 64: per realized piece,
// 2 ds_read_b128 (B-frags, shared by both interleaved tiles) + masked-A
// select + 2 MFMAs per tile. Piece matrices staged in LDS (80 B row stride:
// bank-free). No Bf registers -> 512-thread blocks, 2 blocks/CU = 4
// waves/SIMD (2x round-5 residency). Edges with cc >= PBE are dropped here
// (classifier saturates) and handled exactly by edge_fixup.
// Fragment layouts (m89-verified): A[m=l15][k=q*8+j], B[k=q*8+j][n=l15],
// D[row=q*4+r][col=l15].
// ---------------------------------------------------------------------------
__global__ __launch_bounds__(512) void edge_kernel(
    const float* __restrict__ x, const int* __restrict__ edge_index,
    const float* __restrict__ edge_attr,
    float* __restrict__ out, int E)
{
    // [cc][mat][o(32)][i(40 f16, 32 used)] : 80 B rows, 60 KB total
    __shared__ __align__(16) _Float16 B[PBE * 2 * 32 * 40];
    __shared__ float knl[16];

    const int tid = threadIdx.x;

    // stage piece matrices: 768 rows of 64 B, dst stride 80 B
    for (int r = tid; r < PBE * 2 * 32; r += 512) {
        const float4* s = (const float4*)(g_MK + r * 32);
        float4 a0 = s[0], a1 = s[1], a2 = s[2], a3 = s[3];
        float4* d = (float4*)(B + r * 40);
        d[0] = a0; d[1] = a1; d[2] = a2; d[3] = a3;
    }
    if (tid < 16) knl[tid] = g_ekn[tid];
    __syncthreads();

    float kn[PBE];
#pragma unroll
    for (int j = 0; j < PBE; ++j) kn[j] = knl[j];
    int npc = g_npc[0];
    if (npc > PBE) npc = PBE;

    const int lane  = tid & 63;
    const int w8    = tid >> 6;
    const int gwave = blockIdx.x * 8 + w8;
    const int ot    = gwave & 1;            // which 16-wide output tile
    const int tile0 = gwave >> 1;
    const int tstride = (gridDim.x * 8) >> 1;
    const int q     = lane >> 4;
    const int l15   = lane & 15;
    const int ocol  = ot * 16 + l15;

    // per-lane LDS base for this ocol (per-piece offset added in loop)
    const _Float16* Bbase = B + (size_t)ocol * 40 + q * 8;

    const int numTiles = (E + 15) >> 4;

    for (int tile = tile0; tile < numTiles; tile += 2 * tstride) {
        const int tA = tile;
        const int tB = tile + tstride;
        const bool hasB = (tB < numTiles);

        // ---- two independent input chains ----
        const int eA  = (tA << 4) + l15;
        const bool va = (eA < E);
        const float ta = va ? edge_attr[va ? eA : 0] : 0.f;
        const int colA = va ? edge_index[E + eA] : 0;

        const int eB  = (tB << 4) + l15;
        const bool vb = hasB && (eB < E);
        const float tb = vb ? edge_attr[vb ? eB : 0] : 0.f;
        const int colB = vb ? edge_index[E + (vb ? eB : 0)] : 0;

        const float* xpA = x + (size_t)colA * IC + q * 8;
        const float4 xloA = *(const float4*)(xpA);
        const float4 xhiA = *(const float4*)(xpA + 4);
        const float* xpB = x + (size_t)colB * IC + q * 8;
        const float4 xloB = *(const float4*)(xpB);
        const float4 xhiB = *(const float4*)(xpB + 4);

        int dstsA[4], dstsB[4];
        const int ebaseA = (tA << 4) + q * 4;
        const int ebaseB = (tB << 4) + q * 4;
#pragma unroll
        for (int r = 0; r < 4; ++r) {
            const int erA = ebaseA + r;
            dstsA[r] = (erA < E) ? edge_index[erA] : -1;
            const int erB = ebaseB + r;
            dstsB[r] = (hasB && erB < E) ? edge_index[erB] : -1;
        }

        // piece classification: cc = #knots <= t (saturates at PBE -> fixup)
        int ccA = 0, ccB = 0;
#pragma unroll
        for (int j = 0; j < PBE; ++j) {
            ccA += (ta >= kn[j]) ? 1 : 0;
            ccB += (tb >= kn[j]) ? 1 : 0;
        }

        half8 xhA, xhB;
        xhA[0] = f2h(xloA.x); xhA[1] = f2h(xloA.y);
        xhA[2] = f2h(xloA.z); xhA[3] = f2h(xloA.w);
        xhA[4] = f2h(xhiA.x); xhA[5] = f2h(xhiA.y);
        xhA[6] = f2h(xhiA.z); xhA[7] = f2h(xhiA.w);
        xhB[0] = f2h(xloB.x); xhB[1] = f2h(xloB.y);
        xhB[2] = f2h(xloB.z); xhB[3] = f2h(xloB.w);
        xhB[4] = f2h(xhiB.x); xhB[5] = f2h(xhiB.y);
        xhB[6] = f2h(xhiB.z); xhB[7] = f2h(xhiB.w);

        const _Float16 thA = f2h(ta), thB = f2h(tb);
        const half8 tvA = {thA, thA, thA, thA, thA, thA, thA, thA};
        const half8 tvB = {thB, thB, thB, thB, thB, thB, thB, thB};
        const half8 xtA = xhA * tvA;    // t*x rows (K-matrix operand)
        const half8 xtB = xhB * tvB;
        const half8 z = {0, 0, 0, 0, 0, 0, 0, 0};

        f32x4 accA = {0.f, 0.f, 0.f, 0.f};
        f32x4 accB = {0.f, 0.f, 0.f, 0.f};
        for (int c = 0; c < npc; ++c) {
            const half8 bM = *(const half8*)(Bbase + (size_t)(c * 2 + 0) * 32 * 40);
            const half8 bK = *(const half8*)(Bbase + (size_t)(c * 2 + 1) * 32 * 40);
            const half8 aA1 = (ccA == c) ? xhA : z;
            const half8 aA2 = (ccA == c) ? xtA : z;
            const half8 aB1 = (ccB == c) ? xhB : z;
            const half8 aB2 = (ccB == c) ? xtB : z;
            accA = __builtin_amdgcn_mfma_f32_16x16x32_f16(aA1, bM, accA, 0, 0, 0);
            accB = __builtin_amdgcn_mfma_f32_16x16x32_f16(aB1, bM, accB, 0, 0, 0);
            accA = __builtin_amdgcn_mfma_f32_16x16x32_f16(aA2, bK, accA, 0, 0, 0);
            accB = __builtin_amdgcn_mfma_f32_16x16x32_f16(aB2, bK, accB, 0, 0, 0);
        }

#pragma unroll
        for (int r = 0; r < 4; ++r) {
            if (dstsA[r] >= 0)
                unsafeAtomicAdd(out + (size_t)dstsA[r] * OC + ocol, accA[r]);
        }
#pragma unroll
        for (int r = 0; r < 4; ++r) {
            if (dstsB[r] >= 0)
                unsafeAtomicAdd(out + (size_t)dstsB[r] * OC + ocol, accB[r]);
        }
    }
}

// ---------------------------------------------------------------------------
// Edge fixup: edges with piece index >= PBE (only if npc_e > 12).
// Uniform early-exit; exact scalar path (incl. eb2) with atomics.
// ---------------------------------------------------------------------------
__global__ __launch_bounds__(256) void edge_fixup(
    const float* __restrict__ x, const int* __restrict__ edge_index,
    const float* __restrict__ edge_attr,
    const float* __restrict__ eW1, const float* __restrict__ eb1,
    const float* __restrict__ eW2, const float* __restrict__ eb2,
    float* __restrict__ out, int E)
{
    if (g_npc[0] <= PBE) return;
    const float knb = g_ekn[PBE - 1];   // t >= this knot -> cc >= PBE

    int i0 = blockIdx.x * blockDim.x + threadIdx.x;
    int stride = gridDim.x * blockDim.x;
    for (int e = i0; e < E; e += stride) {
        const float t = edge_attr[e];
        if (t < knb) continue;
        const int col = edge_index[E + e];
        const int dst = edge_index[e];
        float h[HID];
#pragma unroll
        for (int k = 0; k < HID; ++k) {
            float v = fmaf(t, eW1[k], eb1[k]);
            h[k] = v > 0.f ? v : 0.f;
        }
        float xv[IC];
#pragma unroll
        for (int i = 0; i < IC; ++i) xv[i] = x[(size_t)col * IC + i];
        for (int o = 0; o < OC; ++o) {
            float s = 0.f;
            for (int i = 0; i < IC; ++i) {
                float wio = eb2[i * 32 + o];
#pragma unroll
                for (int k = 0; k < HID; ++k)
                    wio = fmaf(h[k], eW2[k * 1024 + i * 32 + o], wio);
                s = fmaf(xv[i], wio, s);
            }
            unsafeAtomicAdd(out + (size_t)dst * OC + o, s);
        }
    }
}

// ---------------------------------------------------------------------------
extern "C" void kernel_launch(void* const* d_in, const int* in_sizes, int n_in,
                              void* d_out, int out_size, void* d_ws, size_t ws_size,
                              hipStream_t stream)
{
    const float* x          = (const float*)d_in[0];
    const int*   edge_index = (const int*)d_in[1];
    const float* edge_attr  = (const float*)d_in[2];
    const int*   angle_index= (const int*)d_in[3];
    const float* angles     = (const float*)d_in[4];
    const float* eW1        = (const float*)d_in[5];
    const float* eb1        = (const float*)d_in[6];
    const float* eW2        = (const float*)d_in[7];
    const float* eb2        = (const float*)d_in[8];
    const float* aW1        = (const float*)d_in[9];
    const float* ab1        = (const float*)d_in[10];
    const float* aW2        = (const float*)d_in[11];
    const float* ab2        = (const float*)d_in[12];
    float* out = (float*)d_out;
    (void)d_ws; (void)ws_size;   // bins live in out[]; mats in device globals

    const int E = in_sizes[1] / 2;
    const int A = in_sizes[3] / 3;
    const int N = in_sizes[0] / IC;

    // 0) knots + piece matrices (both branches)
    setup_kernel<<<96, 256, 0, stream>>>(eW1, eb1, eW2, eb2, aW1, ab1);

    // 1) clear out (doubles as clearing the u64 binning cells)
    const int zblocks = (out_size / 4 + 255) / 256;
    zero_kernel<<<zblocks, 256, 0, stream>>>(out, out_size);

    // 2) bin angles: 1 u64 atomic per angle (knot-compare classify)
    const int sblocks = (A + 255) / 256;
    angle_scatter<<<sblocks, 256, 0, stream>>>(angles, angle_index,
                                               (u64*)out, A);

    // 3) decode cells -> exact angle contribution via MFMA, overwrite rows
    const int gblocks = (N + 63) / 64;
    angle_gather<<<gblocks, 256, 0, stream>>>(out, aW1, ab1, aW2, ab2, N);

    // 4) expected-empty fixup (npc_a > 16 only)
    angle_fixup<<<sblocks, 256, 0, stream>>>(angles, angle_index,
                                             aW1, ab1, aW2, ab2, out, A);

    // 5) edge branch: piecewise W(t), K=64 MFMA, scatter-atomic on top
    edge_kernel<<<512, 512, 0, stream>>>(x, edge_index, edge_attr, out, E);

    // 6) expected-empty fixup (npc_e > 12 only)
    edge_fixup<<<256, 256, 0, stream>>>(x, edge_index, edge_attr,
                                        eW1, eb1, eW2, eb2, out, E);
}

// Round 8
// 155.233 us; speedup vs baseline: 1.3638x; 1.0498x over previous
//
#include <hip/hip_runtime.h>
#include <hip/hip_bf16.h>
#include <stdint.h>

#define IC 32
#define OC 32
#define HID 32

// Angle binning: per node, PBIN u64 cells of (count << TSH | sum of t*2^20).
// count: 20 bits (>= A=400k). t-sum: 44 bits (A*2^20 < 2^39). Cells live in
// a static device buffer (g_cells) -- no aliasing with out, no d_ws.
#define PBIN 16
#define TSH 44
#define TSCALE 1048576.0f   // 2^20

// Edge piecewise path: W(t) = M_c + t*K_c per linear piece c; fast path
// handles up to PBE realized pieces (LDS budget), remainder -> edge fixup.
#define PBE 12
#define MAXN 65536          // g_cells capacity (nodes); N larger -> fallback

typedef __attribute__((ext_vector_type(8))) _Float16 half8;
typedef __attribute__((ext_vector_type(4))) float f32x4;
typedef unsigned long long u64;

static __device__ __forceinline__ _Float16 f2h(float f) { return (_Float16)f; }

// ---------------------------------------------------------------------------
// Device-global scratch (module-load allocated; rewritten in-stream).
// ---------------------------------------------------------------------------
__device__ __align__(16) _Float16 g_MK[PBE * 2 * 32 * 32];
__device__ float g_ekn[16];
__device__ float g_akn[16];
__device__ int   g_npc[2];   // [0]=edge pieces, [1]=angle pieces
__device__ __align__(16) u64 g_cells[(size_t)MAXN * PBIN];   // 8 MB

// ---------------------------------------------------------------------------
// L1: setup (knots + edge piece matrices, blocks < 48) fused with zeroing of
// out and the used cell region (all blocks, grid-stride float4).
//   M_c = eb2 + sum_k on(k,c) b1k eW2k,  K_c = sum_k on(k,c) w1k eW2k
// on(k,c) = (w>0) ? (on0||flip) : (on0&&!flip), flip = realized && rank_k < c.
// ---------------------------------------------------------------------------
__global__ __launch_bounds__(512) void setup_zero(
    const float* __restrict__ eW1, const float* __restrict__ eb1,
    const float* __restrict__ eW2, const float* __restrict__ eb2,
    const float* __restrict__ aW1, const float* __restrict__ ab1,
    float* __restrict__ out, int outF4, int cellF4)
{
    __shared__ float ts_s[32];
    __shared__ int   rk_s[32];
    __shared__ int   re_s[32];
    const int tid = threadIdx.x;
    const int bid = blockIdx.x;

    if (bid < 48) {
        if (bid == 0 && tid < 16) { g_ekn[tid] = 1e30f; g_akn[tid] = 1e30f; }
        if (tid < 32) {   // edge-MLP hinge table (shared: matrices need it)
            const int k = tid;
            const float w = eW1[k], b = eb1[k];
            const float ts = -b / w;
            const bool re = (w != 0.f) && (ts > 0.f) && (ts < 1.f);
            int rk = 0;
            for (int k2 = 0; k2 < 32; ++k2) {
                const float w2 = eW1[k2], b2 = eb1[k2];
                const float t2 = -b2 / w2;
                const bool re2 = (w2 != 0.f) && (t2 > 0.f) && (t2 < 1.f);
                rk += (re2 && (t2 < ts || (t2 == ts && k2 < k))) ? 1 : 0;
            }
            ts_s[k] = ts; rk_s[k] = rk; re_s[k] = re ? 1 : 0;
        }
        __syncthreads();

        if (bid == 0) {
            if (tid < 32) {
                if (re_s[tid]) g_ekn[rk_s[tid]] = ts_s[tid];
                if (tid == 0) {
                    int n = 0;
                    for (int k = 0; k < 32; ++k) n += re_s[k];
                    g_npc[0] = n + 1;
                }
            } else if (tid < 64) {   // angle-MLP knots
                const int k = tid - 32;
                const float w = aW1[k], b = ab1[k];
                const float ts = -b / w;
                const bool re = (w != 0.f) && (ts > 0.f) && (ts < 1.f);
                int rk = 0, nre = 0;
                for (int k2 = 0; k2 < 32; ++k2) {
                    const float w2 = aW1[k2], b2 = ab1[k2];
                    const float t2 = -b2 / w2;
                    const bool re2 = (w2 != 0.f) && (t2 > 0.f) && (t2 < 1.f);
                    nre += re2 ? 1 : 0;
                    rk += (re2 && (t2 < ts || (t2 == ts && k2 < k))) ? 1 : 0;
                }
                if (re) g_akn[rk] = ts;
                if (k == 0) g_npc[1] = nre + 1;
            }
        }

        const int gid = bid * 512 + tid;   // piece-matrix entries (48 blocks)
        if (gid < PBE * 2 * 32 * 32) {
            const int i   = gid & 31;
            const int o   = (gid >> 5) & 31;
            const int mat = (gid >> 10) & 1;
            const int cc  = gid >> 11;
            float acc = (mat == 0) ? eb2[i * 32 + o] : 0.f;
            for (int k = 0; k < 32; ++k) {
                const bool flip = re_s[k] && (rk_s[k] < cc);
                const float w = eW1[k], b = eb1[k];
                const bool on0 = b > 0.f;
                const bool on = (w > 0.f) ? (on0 || flip) : (on0 && !flip);
                if (on) acc = fmaf((mat == 0 ? b : w),
                                   eW2[k * 1024 + i * 32 + o], acc);
            }
            g_MK[((cc * 2 + mat) * 32 + o) * 32 + i] = (_Float16)acc;
        }
    }

    // ---- zero out + used cells (all blocks) ----
    const int total = outF4 + cellF4;
    const float4 z4 = make_float4(0.f, 0.f, 0.f, 0.f);
    for (int i = bid * 512 + tid; i < total; i += gridDim.x * 512) {
        if (i < outF4) ((float4*)out)[i] = z4;
        else           ((float4*)g_cells)[i - outF4] = z4;
    }
}

// ---------------------------------------------------------------------------
// L2: bin angles. cc = #realized knots <= t; one u64 atomic per angle.
// cells == nullptr -> use g_cells (fast path); else caller-provided.
// ---------------------------------------------------------------------------
__global__ __launch_bounds__(256) void angle_scatter(
    const float* __restrict__ angles, const int* __restrict__ angle_index,
    u64* __restrict__ cells, int A)
{
    u64* cp = cells ? cells : g_cells;
    float kn[16];
#pragma unroll
    for (int j = 0; j < 16; ++j) kn[j] = g_akn[j];

    int i0 = blockIdx.x * blockDim.x + threadIdx.x;
    int stride = gridDim.x * blockDim.x;
    for (int a = i0; a < A; a += stride) {
        const float t = angles[a];
        const int j = angle_index[A + a];   // center node
        int cc = 0;
#pragma unroll
        for (int jj = 0; jj < 16; ++jj) cc += (t >= kn[jj]) ? 1 : 0;
        if ((unsigned)cc < (unsigned)PBIN) {
            const u64 enc = ((u64)1 << TSH) | (u64)(unsigned)(t * TSCALE);
            atomicAdd(cp + (size_t)j * PBIN + cc, enc);
        }
    }
}

// ---------------------------------------------------------------------------
// Gather body (proven in R6/R7): per wave 16 nodes; lane (l15,q) builds
// g[k] = sum_c n_c*relu(tb_c*w1k+b1k); two mfma_f32_16x16x32_f16 -> 32 ch.
// addmode: atomicAdd into zeroed out (mega path, concurrent with edge adds);
// else overwrite in-place rows (fallback path, cells==out).
// ---------------------------------------------------------------------------
static __device__ __forceinline__ void angle_gather_wave(
    const u64* __restrict__ cells, float* __restrict__ out,
    const float* __restrict__ aW1, const float* __restrict__ ab1,
    const float* __restrict__ aW2, const float* __restrict__ ab2,
    int N, int base, int lane, bool addmode)
{
    const int q = lane >> 4, l15 = lane & 15;
    float w1s[8], b1s[8];
    int c0 = 0, c1 = 0;
#pragma unroll
    for (int k = 0; k < HID; ++k) {
        const float w = aW1[k], b = ab1[k];
        const bool pos = w > 0.f;
        const bool f0 = pos ? (b > 0.f) : !(b > 0.f);
        const bool f1 = pos ? ((w + b) > 0.f) : !((w + b) > 0.f);
        c0 += f0 ? 1 : 0;
        c1 += f1 ? 1 : 0;
        if ((k >> 3) == q) { w1s[k & 7] = w; b1s[k & 7] = b; }
    }
    int npc = c1 - c0 + 1;
    if (npc > PBIN) npc = PBIN;

    half8 Bf0, Bf1;
#pragma unroll
    for (int j = 0; j < 8; ++j) {
        Bf0[j] = f2h(aW2[(q * 8 + j) * OC + l15]);
        Bf1[j] = f2h(aW2[(q * 8 + j) * OC + 16 + l15]);
    }
    const float bias0 = ab2[l15];
    const float bias1 = ab2[16 + l15];

    const int jn = base + l15;
    const bool vn = (jn < N);
    const u64* cj = cells + (size_t)(vn ? jn : 0) * PBIN;
    float g[8] = {0.f, 0.f, 0.f, 0.f, 0.f, 0.f, 0.f, 0.f};
    float tot = 0.f;
    for (int cc = 0; cc < npc; ++cc) {
        const u64 v = vn ? cj[cc] : 0;
        if (v) {
            const float n  = (float)(unsigned)(v >> TSH);
            const float ts = (float)(v & (((u64)1 << TSH) - 1)) * (1.f / TSCALE);
            const float tb = ts / n;
#pragma unroll
            for (int k = 0; k < 8; ++k) {
                float h = fmaf(tb, w1s[k], b1s[k]);
                h = h > 0.f ? h : 0.f;
                g[k] = fmaf(n, h, g[k]);
            }
            tot += n;
        }
    }
    half8 a;
#pragma unroll
    for (int k = 0; k < 8; ++k) a[k] = f2h(g[k]);

    f32x4 acc0 = {0.f, 0.f, 0.f, 0.f};
    f32x4 acc1 = {0.f, 0.f, 0.f, 0.f};
    acc0 = __builtin_amdgcn_mfma_f32_16x16x32_f16(a, Bf0, acc0, 0, 0, 0);
    acc1 = __builtin_amdgcn_mfma_f32_16x16x32_f16(a, Bf1, acc1, 0, 0, 0);

#pragma unroll
    for (int r = 0; r < 4; ++r) {
        const int node = base + q * 4 + r;
        const float tr = __shfl(tot, q * 4 + r, 64);
        if (node < N) {
            const float v0 = fmaf(tr, bias0, acc0[r]);
            const float v1 = fmaf(tr, bias1, acc1[r]);
            if (addmode) {
                unsafeAtomicAdd(out + (size_t)node * OC + l15, v0);
                unsafeAtomicAdd(out + (size_t)node * OC + 16 + l15, v1);
            } else {
                out[(size_t)node * OC + l15]      = v0;
                out[(size_t)node * OC + 16 + l15] = v1;
            }
        }
    }
}

// Fallback standalone gather (N > MAXN): cells in out, overwrite mode.
__global__ __launch_bounds__(256) void angle_gather_ow(
    float* __restrict__ out,
    const float* __restrict__ aW1, const float* __restrict__ ab1,
    const float* __restrict__ aW2, const float* __restrict__ ab2, int N)
{
    const int lane = threadIdx.x & 63;
    const int wib  = threadIdx.x >> 6;
    const int base = (blockIdx.x * 4 + wib) * 16;
    if (base >= N) return;
    angle_gather_wave((const u64*)out, out, aW1, ab1, aW2, ab2,
                      N, base, lane, false);
}

// ---------------------------------------------------------------------------
// L3: mega kernel -- all post-scatter work as additive block roles:
//   [0,EB):        edge (piecewise W(t), K=64 MFMA, LDS piece matrices)
//   [EB,EB+GB):    angle gather (atomicAdd)
//   [.., +FA):     angle fixup (cc >= PBIN; uniform-empty unless npc_a > 16)
//   [.., +FE):     edge fixup  (cc >= PBE;  uniform-empty unless npc_e > 12)
// All roles add into the zeroed out -> no ordering needed; edge blocks first
// (long pole). __launch_bounds__(512,4) caps VGPR at 128 so fixup scalar
// paths can't sink edge occupancy (LDS 61.5 KB -> 2 blocks/CU, 4 waves/SIMD).
// ---------------------------------------------------------------------------
__global__ __launch_bounds__(512, 4) void mega_kernel(
    const float* __restrict__ x, const int* __restrict__ edge_index,
    const float* __restrict__ edge_attr,
    const float* __restrict__ eW1, const float* __restrict__ eb1,
    const float* __restrict__ eW2, const float* __restrict__ eb2,
    const float* __restrict__ angles, const int* __restrict__ angle_index,
    const float* __restrict__ aW1, const float* __restrict__ ab1,
    const float* __restrict__ aW2, const float* __restrict__ ab2,
    float* __restrict__ out, int E, int A, int N,
    int EB, int GB, int FA, int FE)
{
    // [cc][mat][o(32)][i(40 f16, 32 used)] : 80 B rows (bank-free), 60 KB
    __shared__ __align__(16) _Float16 B[PBE * 2 * 32 * 40];
    __shared__ float knl[16];

    const int tid = threadIdx.x;
    const int bid = blockIdx.x;

    if (bid < EB) {
        // ================= edge role (R7 structure, 8 waves) =================
        for (int r = tid; r < PBE * 2 * 32; r += 512) {
            const float4* s = (const float4*)(g_MK + r * 32);
            float4 a0 = s[0], a1 = s[1], a2 = s[2], a3 = s[3];
            float4* d = (float4*)(B + r * 40);
            d[0] = a0; d[1] = a1; d[2] = a2; d[3] = a3;
        }
        if (tid < 16) knl[tid] = g_ekn[tid];
        __syncthreads();

        float kn[PBE];
#pragma unroll
        for (int j = 0; j < PBE; ++j) kn[j] = knl[j];
        int npc = g_npc[0];
        if (npc > PBE) npc = PBE;

        const int lane  = tid & 63;
        const int w8    = tid >> 6;
        const int gwave = bid * 8 + w8;
        const int ot    = gwave & 1;
        const int tile0 = gwave >> 1;
        const int tstride = (EB * 8) >> 1;
        const int q     = lane >> 4;
        const int l15   = lane & 15;
        const int ocol  = ot * 16 + l15;
        const _Float16* Bbase = B + (size_t)ocol * 40 + q * 8;

        const int numTiles = (E + 15) >> 4;

        for (int tile = tile0; tile < numTiles; tile += 2 * tstride) {
            const int tA = tile;
            const int tB = tile + tstride;
            const bool hasB = (tB < numTiles);

            const int eA  = (tA << 4) + l15;
            const bool va = (eA < E);
            const float ta = va ? edge_attr[eA] : 0.f;
            const int colA = va ? edge_index[E + eA] : 0;

            const int eB  = (tB << 4) + l15;
            const bool vb = hasB && (eB < E);
            const float tb = vb ? edge_attr[eB] : 0.f;
            const int colB = vb ? edge_index[E + eB] : 0;

            const float* xpA = x + (size_t)colA * IC + q * 8;
            const float4 xloA = *(const float4*)(xpA);
            const float4 xhiA = *(const float4*)(xpA + 4);
            const float* xpB = x + (size_t)colB * IC + q * 8;
            const float4 xloB = *(const float4*)(xpB);
            const float4 xhiB = *(const float4*)(xpB + 4);

            int dstsA[4], dstsB[4];
            const int ebaseA = (tA << 4) + q * 4;
            const int ebaseB = (tB << 4) + q * 4;
#pragma unroll
            for (int r = 0; r < 4; ++r) {
                const int erA = ebaseA + r;
                dstsA[r] = (erA < E) ? edge_index[erA] : -1;
                const int erB = ebaseB + r;
                dstsB[r] = (hasB && erB < E) ? edge_index[erB] : -1;
            }

            int ccA = 0, ccB = 0;
#pragma unroll
            for (int j = 0; j < PBE; ++j) {
                ccA += (ta >= kn[j]) ? 1 : 0;
                ccB += (tb >= kn[j]) ? 1 : 0;
            }

            half8 xhA, xhB;
            xhA[0] = f2h(xloA.x); xhA[1] = f2h(xloA.y);
            xhA[2] = f2h(xloA.z); xhA[3] = f2h(xloA.w);
            xhA[4] = f2h(xhiA.x); xhA[5] = f2h(xhiA.y);
            xhA[6] = f2h(xhiA.z); xhA[7] = f2h(xhiA.w);
            xhB[0] = f2h(xloB.x); xhB[1] = f2h(xloB.y);
            xhB[2] = f2h(xloB.z); xhB[3] = f2h(xloB.w);
            xhB[4] = f2h(xhiB.x); xhB[5] = f2h(xhiB.y);
            xhB[6] = f2h(xhiB.z); xhB[7] = f2h(xhiB.w);

            const _Float16 thA = f2h(ta), thB = f2h(tb);
            const half8 tvA = {thA, thA, thA, thA, thA, thA, thA, thA};
            const half8 tvB = {thB, thB, thB, thB, thB, thB, thB, thB};
            const half8 xtA = xhA * tvA;
            const half8 xtB = xhB * tvB;
            const half8 z = {0, 0, 0, 0, 0, 0, 0, 0};

            f32x4 accA = {0.f, 0.f, 0.f, 0.f};
            f32x4 accB = {0.f, 0.f, 0.f, 0.f};
            for (int c = 0; c < npc; ++c) {
                const half8 bM = *(const half8*)(Bbase + (size_t)(c * 2 + 0) * 32 * 40);
                const half8 bK = *(const half8*)(Bbase + (size_t)(c * 2 + 1) * 32 * 40);
                const half8 aA1 = (ccA == c) ? xhA : z;
                const half8 aA2 = (ccA == c) ? xtA : z;
                const half8 aB1 = (ccB == c) ? xhB : z;
                const half8 aB2 = (ccB == c) ? xtB : z;
                accA = __builtin_amdgcn_mfma_f32_16x16x32_f16(aA1, bM, accA, 0, 0, 0);
                accB = __builtin_amdgcn_mfma_f32_16x16x32_f16(aB1, bM, accB, 0, 0, 0);
                accA = __builtin_amdgcn_mfma_f32_16x16x32_f16(aA2, bK, accA, 0, 0, 0);
                accB = __builtin_amdgcn_mfma_f32_16x16x32_f16(aB2, bK, accB, 0, 0, 0);
            }

#pragma unroll
            for (int r = 0; r < 4; ++r) {
                if (dstsA[r] >= 0)
                    unsafeAtomicAdd(out + (size_t)dstsA[r] * OC + ocol, accA[r]);
            }
#pragma unroll
            for (int r = 0; r < 4; ++r) {
                if (dstsB[r] >= 0)
                    unsafeAtomicAdd(out + (size_t)dstsB[r] * OC + ocol, accB[r]);
            }
        }
    } else if (bid < EB + GB) {
        // ================= angle gather role (atomicAdd) ====================
        const int lane = tid & 63;
        const int wib  = tid >> 6;
        const int base = ((bid - EB) * 8 + wib) * 16;
        if (base < N)
            angle_gather_wave(g_cells, out, aW1, ab1, aW2, ab2,
                              N, base, lane, true);
    } else if (bid < EB + GB + FA) {
        // ================= angle fixup role (cc >= PBIN) ====================
        if (g_npc[1] <= PBIN) return;
        const float kn15 = g_akn[15];
        float w1[HID], b1[HID];
#pragma unroll
        for (int k = 0; k < HID; ++k) { w1[k] = aW1[k]; b1[k] = ab1[k]; }
        int i0 = (bid - EB - GB) * 512 + tid;
        int stride = FA * 512;
        for (int a = i0; a < A; a += stride) {
            const float t = angles[a];
            if (t < kn15) continue;
            const int j = angle_index[A + a];
            float h[HID];
#pragma unroll
            for (int k = 0; k < HID; ++k) {
                float v = fmaf(t, w1[k], b1[k]);
                h[k] = v > 0.f ? v : 0.f;
            }
            for (int o = 0; o < OC; ++o) {
                float s = ab2[o];
#pragma unroll
                for (int k = 0; k < HID; ++k) s = fmaf(h[k], aW2[k * OC + o], s);
                unsafeAtomicAdd(out + (size_t)j * OC + o, s);
            }
        }
    } else {
        // ================= edge fixup role (cc >= PBE) ======================
        if (g_npc[0] <= PBE) return;
        const float knb = g_ekn[PBE - 1];
        int i0 = (bid - EB - GB - FA) * 512 + tid;
        int stride = FE * 512;
        for (int e = i0; e < E; e += stride) {
            const float t = edge_attr[e];
            if (t < knb) continue;
            const int col = edge_index[E + e];
            const int dst = edge_index[e];
            float h[HID];
#pragma unroll
            for (int k = 0; k < HID; ++k) {
                float v = fmaf(t, eW1[k], eb1[k]);
                h[k] = v > 0.f ? v : 0.f;
            }
            for (int o = 0; o < OC; ++o) {
                float s = 0.f;
                for (int i = 0; i < IC; ++i) {
                    float wio = eb2[i * 32 + o];
#pragma unroll
                    for (int k = 0; k < HID; ++k)
                        wio = fmaf(h[k], eW2[k * 1024 + i * 32 + o], wio);
                    s = fmaf(x[(size_t)col * IC + i], wio, s);
                }
                unsafeAtomicAdd(out + (size_t)dst * OC + o, s);
            }
        }
    }
}

// ---------------------------------------------------------------------------
extern "C" void kernel_launch(void* const* d_in, const int* in_sizes, int n_in,
                              void* d_out, int out_size, void* d_ws, size_t ws_size,
                              hipStream_t stream)
{
    const float* x          = (const float*)d_in[0];
    const int*   edge_index = (const int*)d_in[1];
    const float* edge_attr  = (const float*)d_in[2];
    const int*   angle_index= (const int*)d_in[3];
    const float* angles     = (const float*)d_in[4];
    const float* eW1        = (const float*)d_in[5];
    const float* eb1        = (const float*)d_in[6];
    const float* eW2        = (const float*)d_in[7];
    const float* eb2        = (const float*)d_in[8];
    const float* aW1        = (const float*)d_in[9];
    const float* ab1        = (const float*)d_in[10];
    const float* aW2        = (const float*)d_in[11];
    const float* ab2        = (const float*)d_in[12];
    float* out = (float*)d_out;
    (void)d_ws; (void)ws_size;

    const int E = in_sizes[1] / 2;
    const int A = in_sizes[3] / 3;
    const int N = in_sizes[0] / IC;

    const int outF4 = out_size / 4;   // out_size is float count
    const int sblocks = (A + 255) / 256;

    if (N <= MAXN) {
        // ---- fast path: 3 launches ----
        const int cellF4 = N * 8;     // N*16 u64 = N*8 float4
        int zg = (outF4 + cellF4 + 511) / 512;
        if (zg < 48) zg = 48;
        setup_zero<<<zg, 512, 0, stream>>>(eW1, eb1, eW2, eb2, aW1, ab1,
                                           out, outF4, cellF4);

        angle_scatter<<<sblocks, 256, 0, stream>>>(angles, angle_index,
                                                   nullptr, A);

        const int EB = 512;
        const int GB = (N + 127) / 128;
        const int FA = 64, FE = 64;
        mega_kernel<<<EB + GB + FA + FE, 512, 0, stream>>>(
            x, edge_index, edge_attr, eW1, eb1, eW2, eb2,
            angles, angle_index, aW1, ab1, aW2, ab2,
            out, E, A, N, EB, GB, FA, FE);
    } else {
        // ---- fallback (N > MAXN): cells in out, gather overwrites ----
        int zg = (outF4 + 511) / 512;
        if (zg < 48) zg = 48;
        setup_zero<<<zg, 512, 0, stream>>>(eW1, eb1, eW2, eb2, aW1, ab1,
                                           out, outF4, 0);
        angle_scatter<<<sblocks, 256, 0, stream>>>(angles, angle_index,
                                                   (u64*)out, A);
        angle_gather_ow<<<(N + 63) / 64, 256, 0, stream>>>(out, aW1, ab1,
                                                           aW2, ab2, N);
        const int EB = 512, FA = 64, FE = 64;
        mega_kernel<<<EB + FA + FE, 512, 0, stream>>>(
            x, edge_index, edge_attr, eW1, eb1, eW2, eb2,
            angles, angle_index, aW1, ab1, aW2, ab2,
            out, E, A, N, EB, 0, FA, FE);
    }
}